// Round 1
// baseline (323.041 us; speedup 1.0000x reference)
//
#include <hip/hip_runtime.h>

typedef __attribute__((ext_vector_type(4))) float floatx4;
typedef __attribute__((ext_vector_type(8))) short short8;
typedef __attribute__((ext_vector_type(4))) unsigned short ushort4v;
typedef __attribute__((ext_vector_type(8))) unsigned short ushort8v;

__device__ __forceinline__ unsigned short f2bf(float f) {
  // round-to-nearest-even fp32 -> bf16 (no NaN inputs expected here)
  unsigned int u = __builtin_bit_cast(unsigned int, f);
  u += 0x7FFFu + ((u >> 16) & 1u);
  return (unsigned short)(u >> 16);
}

#define KTOT 784   // true K (28*28)
#define KP   800   // padded K (25 * 32), pad region zeroed in Bt and in A staging
#define N1   128   // hidden width
#define BM   128   // rows per block
#define BK   32    // K per MFMA step
#define LDA  40    // LDS stride (ushorts) for A/B tiles: 32 + 8 pad (spreads banks)
#define LDH  136   // LDS stride (ushorts) for h / w2t: 128 + 8 pad

// ---------------------------------------------------------------------------
// Prep: W1eff[q][n] = sum_{di,dj} conv_w[di,dj] * w1[(r-di)*26 + (c-dj)][n]
// stored TRANSPOSED as Bt[n][k] bf16, k padded to 800 with zeros.
// ---------------------------------------------------------------------------
__global__ void prep_w1eff(const float* __restrict__ conv_w,
                           const float* __restrict__ w1,
                           unsigned short* __restrict__ Bt) {
  const int n = blockIdx.x;  // 0..127
  float cw[9];
#pragma unroll
  for (int i = 0; i < 9; ++i) cw[i] = conv_w[i];
  for (int q = threadIdx.x; q < KP; q += blockDim.x) {
    float acc = 0.f;
    if (q < KTOT) {
      const int r = q / 28, c = q % 28;
#pragma unroll
      for (int di = 0; di < 3; ++di) {
        const int i2 = r - di;
        if (i2 < 0 || i2 >= 26) continue;
#pragma unroll
        for (int dj = 0; dj < 3; ++dj) {
          const int j2 = c - dj;
          if (j2 < 0 || j2 >= 26) continue;
          acc += cw[di * 3 + dj] * w1[(i2 * 26 + j2) * N1 + n];
        }
      }
    }
    Bt[n * KP + q] = f2bf(acc);
  }
}

// ---------------------------------------------------------------------------
// Fused: out = relu(x @ W1eff + b1) @ w2 + b2
// Block: 256 thr (4 waves, 2x2), BM=128 rows, N=128, K-loop 25 x BK=32.
// Each wave: 4x4 tiles of mfma_f32_16x16x32_bf16 (64 acc VGPRs).
// Epilogue: h -> bf16 LDS -> GEMM2 via MFMA with w2 padded to 16 cols.
// LDS ~60KB -> 2 blocks/CU; grid 512 = exactly 2/CU.
// ---------------------------------------------------------------------------
__global__ __launch_bounds__(256, 2)
void fused_mlp(const float* __restrict__ x,
               const unsigned short* __restrict__ Bt,
               const float* __restrict__ b1,
               const float* __restrict__ w2,
               const float* __restrict__ b2,
               float* __restrict__ out) {
  __shared__ __align__(16) unsigned short sA[BM * LDA];    // 10240 B
  __shared__ __align__(16) unsigned short sB[N1 * LDA];    // 10240 B
  __shared__ __align__(16) unsigned short sH[BM * LDH];    // 34816 B
  __shared__ __align__(16) unsigned short sW2t[16 * LDH];  //  4352 B
  __shared__ float sB1[N1];
  __shared__ float sB2[16];

  const int tid  = threadIdx.x;
  const int wave = tid >> 6;
  const int lane = tid & 63;
  const int wm = wave & 1;   // wave row (2x2 wave grid)
  const int wn = wave >> 1;  // wave col
  const int lr = lane & 15;  // row/col within 16x16 fragment
  const int lq = lane >> 4;  // quad index (k-group / acc row group)

  const long row_base = (long)blockIdx.x * BM;
  const float* xblk = x + row_base * KTOT;

  // preload w2 (transposed, bf16, padded to 16 cols), b1, b2
  for (int i = tid; i < 16 * N1; i += 256) {
    const int n = i >> 7, k = i & 127;
    sW2t[n * LDH + k] = (n < 10) ? f2bf(w2[k * 10 + n]) : (unsigned short)0;
  }
  if (tid < N1) sB1[tid] = b1[tid];
  if (tid < 10) sB2[tid] = b2[tid];

  // staging thread mapping
  const int akp = tid & 7;   // which float4 of the 32-float row chunk
  const int arp = tid >> 3;  // row within a 32-row pass (4 passes)
  const int bkp = tid & 3;   // which ushort8 of the 32-bf16 row chunk
  const int bnp = tid >> 2;  // n within a 64-row pass (2 passes)

  floatx4 acc[4][4] = {};

  for (int kt = 0; kt < 25; ++kt) {
    const int k0 = kt * BK;
    __syncthreads();  // previous iter's fragment reads done
    // stage A: 128 rows x 32 k, fp32 global -> bf16 LDS (coalesced float4)
#pragma unroll
    for (int p = 0; p < 4; ++p) {
      const int row = p * 32 + arp;
      const int kk = k0 + akp * 4;
      floatx4 v = {0.f, 0.f, 0.f, 0.f};
      if (kk < KTOT) v = *(const floatx4*)(xblk + row * KTOT + kk);
      ushort4v u;
      u[0] = f2bf(v[0]); u[1] = f2bf(v[1]); u[2] = f2bf(v[2]); u[3] = f2bf(v[3]);
      *(ushort4v*)&sA[row * LDA + akp * 4] = u;
    }
    // stage B: 128 n x 32 k bf16 (Bt is [n][k], k contiguous)
#pragma unroll
    for (int p = 0; p < 2; ++p) {
      const int n = p * 64 + bnp;
      const ushort8v g = *(const ushort8v*)(Bt + n * KP + k0 + bkp * 8);
      *(ushort8v*)&sB[n * LDA + bkp * 8] = g;
    }
    __syncthreads();
    // fragments + MFMA
    short8 af[4], bfv[4];
#pragma unroll
    for (int i = 0; i < 4; ++i)
      af[i] = *(const short8*)&sA[(wm * 64 + i * 16 + lr) * LDA + lq * 8];
#pragma unroll
    for (int i = 0; i < 4; ++i)
      bfv[i] = *(const short8*)&sB[(wn * 64 + i * 16 + lr) * LDA + lq * 8];
#pragma unroll
    for (int im = 0; im < 4; ++im)
#pragma unroll
      for (int in = 0; in < 4; ++in)
        acc[im][in] = __builtin_amdgcn_mfma_f32_16x16x32_bf16(
            af[im], bfv[in], acc[im][in], 0, 0, 0);
  }

  // h = relu(acc + b1) -> bf16 in sH[row][col]
  // C/D layout (m89/m91): col = lane&15, row = (lane>>4)*4 + reg
#pragma unroll
  for (int im = 0; im < 4; ++im) {
#pragma unroll
    for (int in = 0; in < 4; ++in) {
      const int col = wn * 64 + in * 16 + lr;
      const float bb = sB1[col];
#pragma unroll
      for (int r = 0; r < 4; ++r) {
        const int row = wm * 64 + im * 16 + lq * 4 + r;
        const float v = acc[im][in][r] + bb;
        sH[row * LDH + col] = f2bf(v > 0.f ? v : 0.f);
      }
    }
  }
  __syncthreads();

  // GEMM2: out = h @ w2 + b2. Wave handles rows [wave*32, wave*32+32).
  floatx4 o0 = {0.f, 0.f, 0.f, 0.f}, o1 = {0.f, 0.f, 0.f, 0.f};
  const int m0 = wave * 32;
#pragma unroll
  for (int kc = 0; kc < 4; ++kc) {
    const int kof = kc * 32 + lq * 8;
    const short8 wv = *(const short8*)&sW2t[lr * LDH + kof];
    const short8 a0 = *(const short8*)&sH[(m0 + lr) * LDH + kof];
    const short8 a1 = *(const short8*)&sH[(m0 + 16 + lr) * LDH + kof];
    o0 = __builtin_amdgcn_mfma_f32_16x16x32_bf16(a0, wv, o0, 0, 0, 0);
    o1 = __builtin_amdgcn_mfma_f32_16x16x32_bf16(a1, wv, o1, 0, 0, 0);
  }
  if (lr < 10) {
    const float bb = sB2[lr];
#pragma unroll
    for (int r = 0; r < 4; ++r) {
      const long row = row_base + m0 + lq * 4 + r;
      out[row * 10 + lr] = o0[r] + bb;
      out[(row + 16) * 10 + lr] = o1[r] + bb;
    }
  }
}

extern "C" void kernel_launch(void* const* d_in, const int* in_sizes, int n_in,
                              void* d_out, int out_size, void* d_ws, size_t ws_size,
                              hipStream_t stream) {
  const float* x      = (const float*)d_in[0];  // 65536 x 784
  const float* conv_w = (const float*)d_in[1];  // 3 x 3
  const float* w1     = (const float*)d_in[2];  // 676 x 128
  const float* b1     = (const float*)d_in[3];  // 128
  const float* w2     = (const float*)d_in[4];  // 128 x 10
  const float* b2     = (const float*)d_in[5];  // 10
  float* out = (float*)d_out;                   // 65536 x 10

  unsigned short* Bt = (unsigned short*)d_ws;   // 128 x 800 bf16 = 204800 B

  prep_w1eff<<<128, 256, 0, stream>>>(conv_w, w1, Bt);
  fused_mlp<<<65536 / BM, 256, 0, stream>>>(x, Bt, b1, w2, b2, out);
}

// Round 2
// 306.577 us; speedup vs baseline: 1.0537x; 1.0537x over previous
//
#include <hip/hip_runtime.h>

typedef __attribute__((ext_vector_type(4))) float floatx4;
typedef __attribute__((ext_vector_type(8))) short short8;
typedef __attribute__((ext_vector_type(4))) unsigned short ushort4v;
typedef __attribute__((ext_vector_type(8))) unsigned short ushort8v;

__device__ __forceinline__ unsigned short f2bf(float f) {
  // round-to-nearest-even fp32 -> bf16 (inputs are finite)
  unsigned int u = __builtin_bit_cast(unsigned int, f);
  u += 0x7FFFu + ((u >> 16) & 1u);
  return (unsigned short)(u >> 16);
}

#define KTOT 784   // true K (28*28)
#define KP   800   // padded K (25 * 32); Bt zeros in [784,800)
#define N1   128   // hidden width
#define BM   128   // rows per block
#define BK   32    // K per MFMA step
#define LDA  36    // LDS stride (ushorts) for A/B tiles: 32 + 4 pad (18 dwords, odd/32 spread)
#define LDH  132   // LDS stride (ushorts) for h / w2t: 128 + 4 pad (66 dwords)

// lgkmcnt(0)-only barrier: keeps global (vmcnt) prefetch loads in flight
// across the workgroup barrier (m139-style), unlike __syncthreads which
// drains vmcnt(0).
#define LBAR() do { __builtin_amdgcn_s_waitcnt(0xC07F); __builtin_amdgcn_s_barrier(); } while (0)

// ---------------------------------------------------------------------------
// Prep: W1eff[q][n] = sum_{di,dj} conv_w[di,dj] * w1[(r-di)*26 + (c-dj)][n]
// stored TRANSPOSED as Bt[n][k] bf16, k padded to 800 with zeros.
// ---------------------------------------------------------------------------
__global__ void prep_w1eff(const float* __restrict__ conv_w,
                           const float* __restrict__ w1,
                           unsigned short* __restrict__ Bt) {
  const int n = blockIdx.x;  // 0..127
  float cw[9];
#pragma unroll
  for (int i = 0; i < 9; ++i) cw[i] = conv_w[i];
  for (int q = threadIdx.x; q < KP; q += blockDim.x) {
    float acc = 0.f;
    if (q < KTOT) {
      const int r = q / 28, c = q % 28;
#pragma unroll
      for (int di = 0; di < 3; ++di) {
        const int i2 = r - di;
        if (i2 < 0 || i2 >= 26) continue;
#pragma unroll
        for (int dj = 0; dj < 3; ++dj) {
          const int j2 = c - dj;
          if (j2 < 0 || j2 >= 26) continue;
          acc += cw[di * 3 + dj] * w1[(i2 * 26 + j2) * N1 + n];
        }
      }
    }
    Bt[n * KP + q] = f2bf(acc);
  }
}

// ---------------------------------------------------------------------------
// Fused: out = relu(x @ W1eff + b1) @ w2 + b2
// 256 thr (2x2 waves), BM=128, K-loop 25 x BK=32, register-prefetch
// double-buffered LDS, ONE lgkm-only barrier per K-step.
// ---------------------------------------------------------------------------
__global__ __launch_bounds__(256, 2)
void fused_mlp(const float* __restrict__ x,
               const unsigned short* __restrict__ Bt,
               const float* __restrict__ b1,
               const float* __restrict__ w2,
               const float* __restrict__ b2,
               float* __restrict__ out) {
  __shared__ __align__(16) unsigned short sA[2 * BM * LDA];   // 18432 B
  __shared__ __align__(16) unsigned short sB[2 * N1 * LDA];   // 18432 B
  __shared__ __align__(16) unsigned short sH[BM * LDH];       // 33792 B
  __shared__ __align__(16) unsigned short sW2t[16 * LDH];     //  4224 B
  __shared__ float sB1[N1];
  __shared__ float sB2[16];

  const int tid  = threadIdx.x;
  const int wave = tid >> 6;
  const int lane = tid & 63;
  const int wm = wave & 1;   // wave row (2x2 wave grid)
  const int wn = wave >> 1;  // wave col
  const int lr = lane & 15;  // row/col within 16x16 fragment
  const int lq = lane >> 4;  // quad index (k-group / acc row group)

  const long row_base = (long)blockIdx.x * BM;
  const float* xblk = x + row_base * KTOT;

  // preload w2 (transposed, bf16, padded to 16 cols), b1, b2
  for (int i = tid; i < 16 * N1; i += 256) {
    const int n = i >> 7, k = i & 127;
    sW2t[n * LDH + k] = (n < 10) ? f2bf(w2[k * 10 + n]) : (unsigned short)0;
  }
  if (tid < N1) sB1[tid] = b1[tid];
  if (tid < 10) sB2[tid] = b2[tid];

  // staging thread mapping
  const int akp = tid & 7;   // which float4 of the 32-float row chunk
  const int arp = tid >> 3;  // row within a 32-row pass (4 passes)
  const int bkp = tid & 3;   // which ushort8 of the 32-bf16 row chunk
  const int bnp = tid >> 2;  // n within a 64-row pass (2 passes)

  floatx4 acc[4][4] = {};

  auto load_a = [&](floatx4* pa, int kt) {
    const int k0 = kt * BK;
#pragma unroll
    for (int p = 0; p < 4; ++p) {
      const int row = p * 32 + arp;
      int kk = k0 + akp * 4;
      if (kk >= KTOT) kk = KTOT - 16;  // clamp; k>=784 values killed by Bt zeros
      pa[p] = *(const floatx4*)(xblk + (long)row * KTOT + kk);
    }
  };
  auto load_b = [&](ushort8v* pb, int kt) {
    const int k0 = kt * BK;
#pragma unroll
    for (int p = 0; p < 2; ++p) {
      const int n = p * 64 + bnp;
      pb[p] = *(const ushort8v*)(Bt + n * KP + k0 + bkp * 8);
    }
  };
  auto store_tile = [&](int buf, const floatx4* pa, const ushort8v* pb) {
    unsigned short* A  = sA + buf * (BM * LDA);
    unsigned short* Bs = sB + buf * (N1 * LDA);
#pragma unroll
    for (int p = 0; p < 4; ++p) {
      ushort4v u;
      u[0] = f2bf(pa[p][0]); u[1] = f2bf(pa[p][1]);
      u[2] = f2bf(pa[p][2]); u[3] = f2bf(pa[p][3]);
      *(ushort4v*)&A[(p * 32 + arp) * LDA + akp * 4] = u;
    }
#pragma unroll
    for (int p = 0; p < 2; ++p)
      *(ushort8v*)&Bs[(p * 64 + bnp) * LDA + bkp * 8] = pb[p];
  };
  auto mfma_step = [&](int buf) {
    const unsigned short* A  = sA + buf * (BM * LDA);
    const unsigned short* Bs = sB + buf * (N1 * LDA);
    short8 af[4], bfv[4];
#pragma unroll
    for (int i = 0; i < 4; ++i)
      af[i] = *(const short8*)&A[(wm * 64 + i * 16 + lr) * LDA + lq * 8];
#pragma unroll
    for (int i = 0; i < 4; ++i)
      bfv[i] = *(const short8*)&Bs[(wn * 64 + i * 16 + lr) * LDA + lq * 8];
#pragma unroll
    for (int im = 0; im < 4; ++im)
#pragma unroll
      for (int in = 0; in < 4; ++in)
        acc[im][in] = __builtin_amdgcn_mfma_f32_16x16x32_bf16(
            af[im], bfv[in], acc[im][in], 0, 0, 0);
  };

  // K-loop: register-prefetch double buffer, one lgkm-barrier per step.
  floatx4 pa0[4], pa1[4];
  ushort8v pb0[2], pb1[2];
  load_a(pa0, 0);
  load_b(pb0, 0);
  for (int kt = 0; kt < 24; kt += 2) {
    load_a(pa1, kt + 1);          // prefetch k+1 (stays in flight across LBAR)
    load_b(pb1, kt + 1);
    store_tile(0, pa0, pb0);      // waits only its own (older) vmcnt slots
    LBAR();
    mfma_step(0);
    load_a(pa0, kt + 2);          // prefetch k+2
    load_b(pb0, kt + 2);
    store_tile(1, pa1, pb1);
    LBAR();
    mfma_step(1);
  }
  store_tile(0, pa0, pb0);        // kt = 24
  LBAR();
  mfma_step(0);

  // h = relu(acc + b1) -> bf16 in sH[row][col]
  // C/D layout: col = lane&15, row = (lane>>4)*4 + reg
#pragma unroll
  for (int im = 0; im < 4; ++im) {
#pragma unroll
    for (int in = 0; in < 4; ++in) {
      const int col = wn * 64 + in * 16 + lr;
      const float bb = sB1[col];
#pragma unroll
      for (int r = 0; r < 4; ++r) {
        const int row = wm * 64 + im * 16 + lq * 4 + r;
        const float v = acc[im][in][r] + bb;
        sH[row * LDH + col] = f2bf(v > 0.f ? v : 0.f);
      }
    }
  }
  __syncthreads();  // full drain is fine once, at the epilogue

  // GEMM2: out = h @ w2 + b2. Wave handles rows [wave*32, wave*32+32).
  floatx4 o0 = {0.f, 0.f, 0.f, 0.f}, o1 = {0.f, 0.f, 0.f, 0.f};
  const int m0 = wave * 32;
#pragma unroll
  for (int kc = 0; kc < 4; ++kc) {
    const int kof = kc * 32 + lq * 8;
    const short8 wv = *(const short8*)&sW2t[lr * LDH + kof];
    const short8 a0 = *(const short8*)&sH[(m0 + lr) * LDH + kof];
    const short8 a1 = *(const short8*)&sH[(m0 + 16 + lr) * LDH + kof];
    o0 = __builtin_amdgcn_mfma_f32_16x16x32_bf16(a0, wv, o0, 0, 0, 0);
    o1 = __builtin_amdgcn_mfma_f32_16x16x32_bf16(a1, wv, o1, 0, 0, 0);
  }
  if (lr < 10) {
    const float bb = sB2[lr];
#pragma unroll
    for (int r = 0; r < 4; ++r) {
      const long row = row_base + m0 + lq * 4 + r;
      out[row * 10 + lr] = o0[r] + bb;
      out[(row + 16) * 10 + lr] = o1[r] + bb;
    }
  }
}

extern "C" void kernel_launch(void* const* d_in, const int* in_sizes, int n_in,
                              void* d_out, int out_size, void* d_ws, size_t ws_size,
                              hipStream_t stream) {
  const float* x      = (const float*)d_in[0];  // 65536 x 784
  const float* conv_w = (const float*)d_in[1];  // 3 x 3
  const float* w1     = (const float*)d_in[2];  // 676 x 128
  const float* b1     = (const float*)d_in[3];  // 128
  const float* w2     = (const float*)d_in[4];  // 128 x 10
  const float* b2     = (const float*)d_in[5];  // 10
  float* out = (float*)d_out;                   // 65536 x 10

  unsigned short* Bt = (unsigned short*)d_ws;   // 128 x 800 bf16 = 204800 B

  prep_w1eff<<<128, 256, 0, stream>>>(conv_w, w1, Bt);
  fused_mlp<<<65536 / BM, 256, 0, stream>>>(x, Bt, b1, w2, b2, out);
}